// Round 8
// baseline (65.092 us; speedup 1.0000x reference)
//
#include <hip/hip_runtime.h>
#include <math.h>

// np.float32(sqrt(2)) == 0x3FB504F3
#define SQRT2F   1.41421356237309504880f
#define EPSF     1e-32f
#define BTOL     3e-5f   // fast-path x_log abs error in decision range (|x_log|<=10)
                         // is <~6e-6 (1-ulp v_log + rcp-mul); band is 5x that.

__device__ __forceinline__ float quant_one(float xe, float ze, float ce, float le,
                                           float sc, float rsc, float lo)
{
    // ---- fast f32 estimate of x_log (1 mul, 1 v_log_f32, 1 mul) ----
    float axe_e = fabsf(xe * rsc) + EPSF;
    bool  is_s2 = (ce == SQRT2F);
    float xlg;
    if (is_s2) {
        xlg = 2.0f * __log2f(axe_e);            // log_sqrt2(v) == 2*log2(v)
    } else {
        xlg = __logf(axe_e) / logf(ce);         // generic fallback (unused here)
    }
    float xi = rintf(xlg);
    float t  = xlg - xi;                        // in [-0.5, 0.5]
    if (fabsf(fabsf(t) - 0.5f) < BTOL) {
        // Exact idealized-f32-numpy emulation near the round-half boundary:
        // IEEE f32 div, f32 +eps, correctly-rounded f32 logs, IEEE f32 div,
        // rintf = half-even at the exact f32 tie values.
        float axe = fabsf(xe / sc) + EPSF;
        float L32 = (float)log((double)axe);
        float D32 = (float)log((double)ce);
        xi = rintf(L32 / D32);
    }

    float xc1 = fmaxf(xi - ze, lo);             // clamp(min=lo)
    float xc  = fminf(xc1 - le, -1.0f);         // clamp(max=-1)
    float e   = xc + le + ze;                   // integer in [-1,9] unless zeroed

    float q;
    if (is_s2) {
        // approx_factor * sqrt(2) == 1.5 exactly:
        //   e even: q = 2^(e/2);  e odd: q = 1.5 * 2^((e-1)/2)   (both exact)
        int ei = (int)e;
        q = (ei & 1) ? ldexpf(1.5f, (ei - 1) >> 1)
                     : ldexpf(1.0f, ei >> 1);
    } else {
        q = powf(ce, e);
    }

    q = copysignf(q, xe);                       // s=sign(x); x==0 is zero-flagged below
    if (xc1 <= lo) q = 0.0f;                    // zero_flag
    return q * sc;
}

// C=4096 rows, F=4096 cols; 2 float4 per thread, second at +blockDim lanes so
// EVERY load instruction is 16B/lane wave-contiguous (unlike round 6's stride bug).
__global__ __launch_bounds__(256) void uaq_kernel(
    const float4* __restrict__ x,
    const float*  __restrict__ scale,     // (C,)
    const float4* __restrict__ zero,
    const float4* __restrict__ code,
    const float4* __restrict__ level,
    const float*  __restrict__ asym,      // (C,)
    float4* __restrict__ out,
    int n4)
{
    int base = blockIdx.x * (blockDim.x * 2) + threadIdx.x;
    int idx[2] = { base, base + (int)blockDim.x };

    // issue all 8 input loads before any compute (MLP)
    float4 xv[2], zv[2], cv[2], lv[2];
    float  sc[2], as[2];
    #pragma unroll
    for (int h = 0; h < 2; ++h) {
        int i = idx[h];
        if (i < n4) {
            xv[h] = x[i];  zv[h] = zero[i];  cv[h] = code[i];  lv[h] = level[i];
            int row = i >> 10;               // F/4 = 1024 float4 per row
            sc[h] = scale[row];
            as[h] = asym[row];
        }
    }

    #pragma unroll
    for (int h = 0; h < 2; ++h) {
        int i = idx[h];
        if (i >= n4) continue;
        float s   = sc[h];
        float rsc = 1.0f / s;                        // one IEEE div per 4 elems
        float lo  = fmaf(-0.5f, as[h], -1.0f);       // exact for asym in {0,1}
        float4 ov;
        ov.x = quant_one(xv[h].x, zv[h].x, cv[h].x, lv[h].x, s, rsc, lo);
        ov.y = quant_one(xv[h].y, zv[h].y, cv[h].y, lv[h].y, s, rsc, lo);
        ov.z = quant_one(xv[h].z, zv[h].z, cv[h].z, lv[h].z, s, rsc, lo);
        ov.w = quant_one(xv[h].w, zv[h].w, cv[h].w, lv[h].w, s, rsc, lo);
        out[i] = ov;
    }
}

extern "C" void kernel_launch(void* const* d_in, const int* in_sizes, int n_in,
                              void* d_out, int out_size, void* d_ws, size_t ws_size,
                              hipStream_t stream) {
    const float* x     = (const float*)d_in[0];
    const float* scale = (const float*)d_in[1];
    const float* zero  = (const float*)d_in[2];
    const float* code  = (const float*)d_in[3];
    const float* level = (const float*)d_in[4];
    const float* asym  = (const float*)d_in[5];
    float* out = (float*)d_out;

    int n  = out_size;          // 4096*4096
    int n4 = n / 4;

    int block = 256;
    int per_block = block * 2;  // 2 float4 per thread
    int grid  = (n4 + per_block - 1) / per_block;

    uaq_kernel<<<grid, block, 0, stream>>>(
        (const float4*)x, scale, (const float4*)zero, (const float4*)code,
        (const float4*)level, asym, (float4*)out, n4);
}